// Round 5
// baseline (204.848 us; speedup 1.0000x reference)
//
#include <hip/hip_runtime.h>

// x (4096, 2, 1024) fp32.  P_i = x[i,0,:], A_j = x[i,1,:]
// out[0] = 1.0 exactly; out[1] = prec1 = 100*mean(argmax_j sim[i,j] == i)
// argmax_j sim[i,j] == argmax_j dot(P_i,A_j)*inv_norm(A_j).
// R5: R4 structure with occupancy fixed. 256x128 block tile (grid 16x32 =
// 512 blocks = 2 blocks/CU), 4 waves of 128x64 (acc=128 regs -> 2 waves/SIMD),
// 32x32x16 bf16 MFMA 3-pass split, BK=16, double-buffered 2x24KB LDS.

#define NROWS 4096
#define DDIM  1024
#define XSTR  2048

typedef unsigned int u32;
typedef unsigned long long u64;
typedef __attribute__((ext_vector_type(8))) short bf16x8;
typedef __attribute__((ext_vector_type(16))) float f32x16;

#define GLOBAL_AS __attribute__((address_space(1)))
#define LDS_AS    __attribute__((address_space(3)))

__device__ __forceinline__ void async_load16(const void* g, void* l) {
    __builtin_amdgcn_global_load_lds((GLOBAL_AS const u32*)g, (LDS_AS u32*)l, 16, 0, 0);
}

__device__ __forceinline__ unsigned int fkey(float f) {
    unsigned int u = __float_as_uint(f);
    return (u & 0x80000000u) ? ~u : (u | 0x80000000u);
}

__device__ __forceinline__ u64 shfl_xor_u64(u64 v, int m) {
    unsigned int lo = (unsigned int)v;
    unsigned int hi = (unsigned int)(v >> 32);
    lo = __shfl_xor(lo, m, 64);
    hi = __shfl_xor(hi, m, 64);
    return ((u64)hi << 32) | lo;
}

__device__ __forceinline__ unsigned short f2bf(float f) {
    unsigned u = __float_as_uint(f);
    return (unsigned short)((u + 0x7FFFu + ((u >> 16) & 1u)) >> 16);
}

__device__ __forceinline__ void split4(float4 v, ushort4* h, ushort4* l) {
    float f[4] = {v.x, v.y, v.z, v.w};
    unsigned short hh[4], ll[4];
#pragma unroll
    for (int q = 0; q < 4; ++q) {
        hh[q] = f2bf(f[q]);
        float hf = __uint_as_float(((unsigned)hh[q]) << 16);
        ll[q] = f2bf(f[q] - hf);
    }
    *h = make_ushort4(hh[0], hh[1], hh[2], hh[3]);
    *l = make_ushort4(ll[0], ll[1], ll[2], ll[3]);
}

// Workspace layout (bytes):
#define PHI_OFF 0u
#define PLO_OFF 8388608u
#define AHI_OFF 16777216u
#define ALO_OFF 25165824u
#define INV_OFF 33554432u
#define PCK_OFF 33570816u
#define WS_NEED 33603584u

// Prep: one block per row. Split fp32 -> (hi,lo) bf16 for P and A,
// block-reduce anchor norm, zero packed[row].
__global__ __launch_bounds__(256) void prep_kernel(const float* __restrict__ x,
                                                   unsigned short* __restrict__ Phi,
                                                   unsigned short* __restrict__ Plo,
                                                   unsigned short* __restrict__ Ahi,
                                                   unsigned short* __restrict__ Alo,
                                                   float* __restrict__ inv_an,
                                                   u64* __restrict__ packed) {
    __shared__ float red[4];
    const int b = blockIdx.x;
    const int t = threadIdx.x;

    float4 pv = *(const float4*)(x + (size_t)b * XSTR + t * 4);
    float4 av = *(const float4*)(x + (size_t)b * XSTR + DDIM + t * 4);

    ushort4 h, l;
    split4(pv, &h, &l);
    ((ushort4*)Phi)[(size_t)b * 256 + t] = h;
    ((ushort4*)Plo)[(size_t)b * 256 + t] = l;
    split4(av, &h, &l);
    ((ushort4*)Ahi)[(size_t)b * 256 + t] = h;
    ((ushort4*)Alo)[(size_t)b * 256 + t] = l;

    float s = av.x * av.x + av.y * av.y + av.z * av.z + av.w * av.w;
#pragma unroll
    for (int off = 32; off > 0; off >>= 1) s += __shfl_down(s, off, 64);
    if ((t & 63) == 0) red[t >> 6] = s;
    __syncthreads();
    if (t == 0) {
        inv_an[b] = 1.0f / sqrtf(red[0] + red[1] + red[2] + red[3]);
        packed[b] = 0ULL;
    }
}

// MFMA GEMM + argmax. 256x128 block tile, 4 waves (2x2) of 128x64.
// LDS per buffer (24KB = 24 segs x 1KB): [Phi 8][Plo 8][Ahi 4][Alo 4].
// Segment = 32 rows x 16 k: (row r, khalf q) at byte q*512 + r*16 — the
// order global_load_lds produces (lane i = q*32 + r writes base + i*16).
// Waves 0/1 stage Phi/Plo (8 segs); waves 2/3 stage Ahi/Alo (4 segs).
__global__ __launch_bounds__(256, 2) void mfma_gemm_argmax(const unsigned short* __restrict__ Phi,
                                                           const unsigned short* __restrict__ Plo,
                                                           const unsigned short* __restrict__ Ahi,
                                                           const unsigned short* __restrict__ Alo,
                                                           const float* __restrict__ inv_an,
                                                           u64* __restrict__ packed) {
    __shared__ __align__(16) unsigned short lds[24576];  // 2 bufs x 12288 ushort (24KB each)

    const int r0 = blockIdx.x * 256;
    const int c0 = blockIdx.y * 128;
    const int wave = threadIdx.x >> 6;
    const int lane = threadIdx.x & 63;
    const int l31 = lane & 31;
    const int lh = lane >> 5;
    const int wm = wave & 1;   // m-half: rows wm*128..+127
    const int wn = wave >> 1;  // n-half: cols wn*64..+63

    // ---- staging setup ----
    const unsigned short* srcs[4] = {Phi, Plo, Ahi, Alo};
    const int nseg = (wave < 2) ? 8 : 4;
    const int woff = (wave < 2) ? wave * 4096 : 8192 + (wave - 2) * 2048;  // ushort units
    const char* gp[8];
    {
        const unsigned short* src = srcs[wave];
        const int baserow = (wave < 2) ? r0 : c0;
#pragma unroll
        for (int rb = 0; rb < 8; ++rb) {
            int rr = (rb < nseg) ? rb : 0;
            gp[rb] = (const char*)(src + (size_t)(baserow + rr * 32 + l31) * DDIM) + lh * 16;
        }
    }

    // frag read offset within a 1KB segment (ushort units): byte lh*512+l31*16
    const int lof = lh * 256 + l31 * 8;

    f32x16 zero16 = {0.f,0.f,0.f,0.f,0.f,0.f,0.f,0.f,0.f,0.f,0.f,0.f,0.f,0.f,0.f,0.f};
    f32x16 acc[4][2];
#pragma unroll
    for (int i = 0; i < 4; ++i)
#pragma unroll
        for (int j = 0; j < 2; ++j) acc[i][j] = zero16;

    float ian[2];
#pragma unroll
    for (int nt = 0; nt < 2; ++nt) ian[nt] = inv_an[c0 + wn * 64 + nt * 32 + l31];

    // prologue: stage chunk 0 -> buf 0
    if (wave < 2) {
#pragma unroll
        for (int rb = 0; rb < 8; ++rb) async_load16(gp[rb], lds + woff + rb * 512);
    } else {
#pragma unroll
        for (int rb = 0; rb < 4; ++rb) async_load16(gp[rb], lds + woff + rb * 512);
    }

    for (int kc = 0; kc < 64; ++kc) {
        __syncthreads();  // vmcnt drain: chunk kc staged; prev compute done
        const int cur = (kc & 1) * 12288;
        if (kc < 63) {
            const int nxt = ((kc + 1) & 1) * 12288;
            const int gofs = (kc + 1) * 32;  // bytes: 16 k * 2B
            if (wave < 2) {
#pragma unroll
                for (int rb = 0; rb < 8; ++rb)
                    async_load16(gp[rb] + gofs, lds + nxt + woff + rb * 512);
            } else {
#pragma unroll
                for (int rb = 0; rb < 4; ++rb)
                    async_load16(gp[rb] + gofs, lds + nxt + woff + rb * 512);
            }
        }

        bf16x8 ph[4], pl[4], ah[2], al[2];
#pragma unroll
        for (int t = 0; t < 4; ++t) {
            const int prb = wm * 4 + t;
            ph[t] = *(const bf16x8*)(lds + cur + prb * 512 + lof);
            pl[t] = *(const bf16x8*)(lds + cur + 4096 + prb * 512 + lof);
        }
#pragma unroll
        for (int t = 0; t < 2; ++t) {
            const int arb = wn * 2 + t;
            ah[t] = *(const bf16x8*)(lds + cur + 8192 + arb * 512 + lof);
            al[t] = *(const bf16x8*)(lds + cur + 10240 + arb * 512 + lof);
        }
#pragma unroll
        for (int mt = 0; mt < 4; ++mt)
#pragma unroll
            for (int nt = 0; nt < 2; ++nt)
                acc[mt][nt] = __builtin_amdgcn_mfma_f32_32x32x16_bf16(ph[mt], ah[nt], acc[mt][nt], 0, 0, 0);
#pragma unroll
        for (int mt = 0; mt < 4; ++mt)
#pragma unroll
            for (int nt = 0; nt < 2; ++nt)
                acc[mt][nt] = __builtin_amdgcn_mfma_f32_32x32x16_bf16(ph[mt], al[nt], acc[mt][nt], 0, 0, 0);
#pragma unroll
        for (int mt = 0; mt < 4; ++mt)
#pragma unroll
            for (int nt = 0; nt < 2; ++nt)
                acc[mt][nt] = __builtin_amdgcn_mfma_f32_32x32x16_bf16(pl[mt], ah[nt], acc[mt][nt], 0, 0, 0);
    }

    // ---- epilogue ----
    // 32x32 C/D layout (m74/m101): col = lane&31, row = (reg&3)+8*(reg>>2)+4*(lane>>5)
#pragma unroll
    for (int mt = 0; mt < 4; ++mt)
#pragma unroll
        for (int reg = 0; reg < 16; ++reg) {
            const int row = r0 + wm * 128 + mt * 32 + (reg & 3) + 8 * (reg >> 2) + 4 * lh;
            u64 best = 0ULL;
#pragma unroll
            for (int nt = 0; nt < 2; ++nt) {
                const int col = c0 + wn * 64 + nt * 32 + l31;
                const float v = acc[mt][nt][reg] * ian[nt];
                const u64 p = ((u64)fkey(v) << 32) | (unsigned int)(~col);
                best = best > p ? best : p;
            }
#pragma unroll
            for (int m = 1; m <= 16; m <<= 1) {
                const u64 o = shfl_xor_u64(best, m);
                best = best > o ? best : o;
            }
            if (l31 == 0) atomicMax(&packed[row], best);
        }
}

// ---------------- fallback fp32 path (proven R1) ----------------
__global__ __launch_bounds__(256) void norms_kernel(const float* __restrict__ x,
                                                    float* __restrict__ inv_an,
                                                    u64* __restrict__ packed) {
    int gid  = blockIdx.x * 256 + threadIdx.x;
    int j    = gid >> 6;
    int lane = threadIdx.x & 63;
    if (gid < NROWS) packed[gid] = 0ULL;
    const float4* a = (const float4*)(x + (size_t)j * XSTR + DDIM);
    float s = 0.0f;
#pragma unroll
    for (int i = 0; i < 4; ++i) {
        float4 v = a[lane + i * 64];
        s += v.x * v.x + v.y * v.y + v.z * v.z + v.w * v.w;
    }
#pragma unroll
    for (int off = 32; off > 0; off >>= 1) s += __shfl_down(s, off, 64);
    if (lane == 0) inv_an[j] = 1.0f / sqrtf(s);
}

__global__ __launch_bounds__(256) void gemm_argmax_kernel(const float* __restrict__ x,
                                                          const float* __restrict__ inv_an,
                                                          u64* __restrict__ packed) {
    __shared__ __align__(16) float Pt[16][128];
    __shared__ __align__(16) float At[16][128];
    const int r0 = blockIdx.x * 128;
    const int c0 = blockIdx.y * 128;
    const int t = threadIdx.x;
    const int tx = t & 15;
    const int ty = t >> 4;
    const int srow = t >> 1;
    const int skq = (t & 1) * 8;
    float acc[8][8];
#pragma unroll
    for (int r = 0; r < 8; ++r)
#pragma unroll
        for (int c = 0; c < 8; ++c) acc[r][c] = 0.0f;
    const float* gp = x + (size_t)(r0 + srow) * XSTR + skq;
    const float* ga = x + (size_t)(c0 + srow) * XSTR + DDIM + skq;
    for (int k0 = 0; k0 < DDIM; k0 += 16) {
        __syncthreads();
        float4 p0 = *(const float4*)(gp + k0);
        float4 p1 = *(const float4*)(gp + k0 + 4);
        float4 a0 = *(const float4*)(ga + k0);
        float4 a1 = *(const float4*)(ga + k0 + 4);
        Pt[skq + 0][srow] = p0.x; Pt[skq + 1][srow] = p0.y;
        Pt[skq + 2][srow] = p0.z; Pt[skq + 3][srow] = p0.w;
        Pt[skq + 4][srow] = p1.x; Pt[skq + 5][srow] = p1.y;
        Pt[skq + 6][srow] = p1.z; Pt[skq + 7][srow] = p1.w;
        At[skq + 0][srow] = a0.x; At[skq + 1][srow] = a0.y;
        At[skq + 2][srow] = a0.z; At[skq + 3][srow] = a0.w;
        At[skq + 4][srow] = a1.x; At[skq + 5][srow] = a1.y;
        At[skq + 6][srow] = a1.z; At[skq + 7][srow] = a1.w;
        __syncthreads();
#pragma unroll
        for (int kk = 0; kk < 16; ++kk) {
            float pr[8], ar[8];
            *(float4*)&pr[0] = *(const float4*)&Pt[kk][ty * 8];
            *(float4*)&pr[4] = *(const float4*)&Pt[kk][ty * 8 + 4];
            *(float4*)&ar[0] = *(const float4*)&At[kk][tx * 8];
            *(float4*)&ar[4] = *(const float4*)&At[kk][tx * 8 + 4];
#pragma unroll
            for (int r = 0; r < 8; ++r)
#pragma unroll
                for (int c = 0; c < 8; ++c) acc[r][c] += pr[r] * ar[c];
        }
    }
    float ian[8];
#pragma unroll
    for (int c = 0; c < 8; ++c) ian[c] = inv_an[c0 + tx * 8 + c];
#pragma unroll
    for (int r = 0; r < 8; ++r) {
        int row = r0 + ty * 8 + r;
        u64 best = 0ULL;
#pragma unroll
        for (int c = 0; c < 8; ++c) {
            int col = c0 + tx * 8 + c;
            float v = acc[r][c] * ian[c];
            u64 p = ((u64)fkey(v) << 32) | (unsigned int)(~col);
            best = best > p ? best : p;
        }
#pragma unroll
        for (int m = 1; m <= 8; m <<= 1) {
            u64 o = shfl_xor_u64(best, m);
            best = best > o ? best : o;
        }
        if (tx == 0) atomicMax(&packed[row], best);
    }
}

// ---------------- finalize ----------------
__global__ __launch_bounds__(256) void finalize_kernel(const u64* __restrict__ packed,
                                                       float* __restrict__ out) {
    __shared__ int cnt_s;
    int t = threadIdx.x;
    if (t == 0) cnt_s = 0;
    __syncthreads();
    int c = 0;
    for (int r = t; r < NROWS; r += 256) {
        unsigned int col = ~(unsigned int)(packed[r] & 0xFFFFFFFFULL);
        c += (col == (unsigned int)r) ? 1 : 0;
    }
#pragma unroll
    for (int off = 32; off > 0; off >>= 1) c += __shfl_down(c, off, 64);
    if ((t & 63) == 0) atomicAdd(&cnt_s, c);
    __syncthreads();
    if (t == 0) {
        out[0] = 1.0f;
        out[1] = 100.0f * (float)cnt_s / (float)NROWS;
    }
}

extern "C" void kernel_launch(void* const* d_in, const int* in_sizes, int n_in,
                              void* d_out, int out_size, void* d_ws, size_t ws_size,
                              hipStream_t stream) {
    (void)in_sizes; (void)n_in; (void)out_size;
    const float* x = (const float*)d_in[0];
    float* out = (float*)d_out;

    if (ws_size >= (size_t)WS_NEED) {
        char* ws = (char*)d_ws;
        unsigned short* Phi = (unsigned short*)(ws + PHI_OFF);
        unsigned short* Plo = (unsigned short*)(ws + PLO_OFF);
        unsigned short* Ahi = (unsigned short*)(ws + AHI_OFF);
        unsigned short* Alo = (unsigned short*)(ws + ALO_OFF);
        float* inv_an = (float*)(ws + INV_OFF);
        u64* packed = (u64*)(ws + PCK_OFF);

        prep_kernel<<<NROWS, 256, 0, stream>>>(x, Phi, Plo, Ahi, Alo, inv_an, packed);
        dim3 grid(NROWS / 256, NROWS / 128);
        mfma_gemm_argmax<<<grid, 256, 0, stream>>>(Phi, Plo, Ahi, Alo, inv_an, packed);
        finalize_kernel<<<1, 256, 0, stream>>>(packed, out);
    } else {
        float* inv_an = (float*)d_ws;
        u64* packed = (u64*)((char*)d_ws + NROWS * sizeof(float));
        norms_kernel<<<NROWS / 4, 256, 0, stream>>>(x, inv_an, packed);
        dim3 grid(NROWS / 128, NROWS / 128);
        gemm_argmax_kernel<<<grid, 256, 0, stream>>>(x, inv_an, packed);
        finalize_kernel<<<1, 256, 0, stream>>>(packed, out);
    }
}

// Round 6
// 162.503 us; speedup vs baseline: 1.2606x; 1.2606x over previous
//
#include <hip/hip_runtime.h>

// x (4096, 2, 1024) fp32.  P_i = x[i,0,:], A_j = x[i,1,:]
// out[0] = 1.0 exactly; out[1] = prec1 = 100*mean(argmax_j sim[i,j] == i)
// argmax_j sim[i,j] == argmax_j dot(P_i,A_j)*inv_norm(A_j).
// R6: 2-pass bf16-split MFMA: dot ~= Phi*Ahi + Phi*Alo (drop Pl*A,
// sigma ~3.5e-5 sim-units vs top-2 gaps ~8e-3). R4's verified 256x256
// structure (4 waves of 128x128, 32x32x16 MFMA, BK=16, double-buffered
// LDS, grid 256 = 1 block/CU); LDS now 3 arrays x 8 segs = 2x24KB.

#define NROWS 4096
#define DDIM  1024
#define XSTR  2048

typedef unsigned int u32;
typedef unsigned long long u64;
typedef __attribute__((ext_vector_type(8))) short bf16x8;
typedef __attribute__((ext_vector_type(16))) float f32x16;

#define GLOBAL_AS __attribute__((address_space(1)))
#define LDS_AS    __attribute__((address_space(3)))

__device__ __forceinline__ void async_load16(const void* g, void* l) {
    __builtin_amdgcn_global_load_lds((GLOBAL_AS const u32*)g, (LDS_AS u32*)l, 16, 0, 0);
}

__device__ __forceinline__ unsigned int fkey(float f) {
    unsigned int u = __float_as_uint(f);
    return (u & 0x80000000u) ? ~u : (u | 0x80000000u);
}

__device__ __forceinline__ u64 shfl_xor_u64(u64 v, int m) {
    unsigned int lo = (unsigned int)v;
    unsigned int hi = (unsigned int)(v >> 32);
    lo = __shfl_xor(lo, m, 64);
    hi = __shfl_xor(hi, m, 64);
    return ((u64)hi << 32) | lo;
}

__device__ __forceinline__ unsigned short f2bf(float f) {
    unsigned u = __float_as_uint(f);
    return (unsigned short)((u + 0x7FFFu + ((u >> 16) & 1u)) >> 16);
}

__device__ __forceinline__ void split4(float4 v, ushort4* h, ushort4* l) {
    float f[4] = {v.x, v.y, v.z, v.w};
    unsigned short hh[4], ll[4];
#pragma unroll
    for (int q = 0; q < 4; ++q) {
        hh[q] = f2bf(f[q]);
        float hf = __uint_as_float(((unsigned)hh[q]) << 16);
        ll[q] = f2bf(f[q] - hf);
    }
    *h = make_ushort4(hh[0], hh[1], hh[2], hh[3]);
    *l = make_ushort4(ll[0], ll[1], ll[2], ll[3]);
}

// Workspace layout (bytes):
#define PHI_OFF 0u
#define AHI_OFF 8388608u
#define ALO_OFF 16777216u
#define INV_OFF 25165824u
#define PCK_OFF 25182208u
#define WS_NEED 25214976u

// Prep: one block per row. Phi = bf16(P); A split into (Ahi, Alo);
// block-reduce anchor norm (from fp32); zero packed[row].
__global__ __launch_bounds__(256) void prep_kernel(const float* __restrict__ x,
                                                   unsigned short* __restrict__ Phi,
                                                   unsigned short* __restrict__ Ahi,
                                                   unsigned short* __restrict__ Alo,
                                                   float* __restrict__ inv_an,
                                                   u64* __restrict__ packed) {
    __shared__ float red[4];
    const int b = blockIdx.x;
    const int t = threadIdx.x;

    float4 pv = *(const float4*)(x + (size_t)b * XSTR + t * 4);
    float4 av = *(const float4*)(x + (size_t)b * XSTR + DDIM + t * 4);

    ushort4 ph = make_ushort4(f2bf(pv.x), f2bf(pv.y), f2bf(pv.z), f2bf(pv.w));
    ((ushort4*)Phi)[(size_t)b * 256 + t] = ph;

    ushort4 h, l;
    split4(av, &h, &l);
    ((ushort4*)Ahi)[(size_t)b * 256 + t] = h;
    ((ushort4*)Alo)[(size_t)b * 256 + t] = l;

    float s = av.x * av.x + av.y * av.y + av.z * av.z + av.w * av.w;
#pragma unroll
    for (int off = 32; off > 0; off >>= 1) s += __shfl_down(s, off, 64);
    if ((t & 63) == 0) red[t >> 6] = s;
    __syncthreads();
    if (t == 0) {
        inv_an[b] = 1.0f / sqrtf(red[0] + red[1] + red[2] + red[3]);
        packed[b] = 0ULL;
    }
}

// MFMA GEMM + argmax. 256x256 block tile, 4 waves (2x2) of 128x128.
// 32x32x16 bf16 MFMA, BK=16, double-buffered 2x24KB LDS.
// LDS per buffer (24 segs x 1KB): [Phi 8][Ahi 8][Alo 8]. Segment = 32 rows
// x 16 k: (row r, khalf q) at byte q*512 + r*16 — the order global_load_lds
// produces (lane i = q*32 + r writes base + i*16). Waves 0..2 stage arrays
// 0..2 (8 segs each); wave 3 stages nothing.
__global__ __launch_bounds__(256, 1) void mfma_gemm_argmax(const unsigned short* __restrict__ Phi,
                                                           const unsigned short* __restrict__ Ahi,
                                                           const unsigned short* __restrict__ Alo,
                                                           const float* __restrict__ inv_an,
                                                           u64* __restrict__ packed) {
    __shared__ __align__(16) unsigned short lds[24576];  // 2 bufs x 12288 ushort (24KB each)

    const int r0 = blockIdx.x * 256;
    const int c0 = blockIdx.y * 256;
    const int wave = threadIdx.x >> 6;
    const int lane = threadIdx.x & 63;
    const int l31 = lane & 31;
    const int lh = lane >> 5;
    const int wm = wave & 1;   // m-half: rows wm*128..+127
    const int wn = wave >> 1;  // n-half: cols wn*128..+127

    // ---- staging: wave w<3 stages array w (8 x 1KB segments per chunk) ----
    const unsigned short* srcs[3] = {Phi, Ahi, Alo};
    const char* gp[8];
    if (wave < 3) {
        const unsigned short* src = srcs[wave];
        const int baserow = (wave == 0) ? r0 : c0;
#pragma unroll
        for (int rb = 0; rb < 8; ++rb)
            gp[rb] = (const char*)(src + (size_t)(baserow + rb * 32 + l31) * DDIM) + lh * 16;
    }
    unsigned short* myseg = lds + wave * 4096;  // valid for wave<3

    // frag read offset within a 1KB segment (ushort units): byte lh*512+l31*16
    const int lof = lh * 256 + l31 * 8;

    f32x16 zero16 = {0.f,0.f,0.f,0.f,0.f,0.f,0.f,0.f,0.f,0.f,0.f,0.f,0.f,0.f,0.f,0.f};
    f32x16 acc[4][4];
#pragma unroll
    for (int i = 0; i < 4; ++i)
#pragma unroll
        for (int j = 0; j < 4; ++j) acc[i][j] = zero16;

    float ian[4];
#pragma unroll
    for (int nt = 0; nt < 4; ++nt) ian[nt] = inv_an[c0 + wn * 128 + nt * 32 + l31];

    // prologue: stage chunk 0 -> buf 0
    if (wave < 3) {
#pragma unroll
        for (int rb = 0; rb < 8; ++rb) async_load16(gp[rb], myseg + rb * 512);
    }

    for (int kc = 0; kc < 64; ++kc) {
        __syncthreads();  // staging waves drained vmcnt; chunk kc visible
        const int cur = (kc & 1) * 12288;
        if (kc < 63 && wave < 3) {
            const int nxt = ((kc + 1) & 1) * 12288;
            const int gofs = (kc + 1) * 32;  // bytes: 16 k * 2B
#pragma unroll
            for (int rb = 0; rb < 8; ++rb)
                async_load16(gp[rb] + gofs, lds + nxt + wave * 4096 + rb * 512);
        }

        bf16x8 ph[4], ah[4], al[4];
#pragma unroll
        for (int t = 0; t < 4; ++t) {
            const int prb = wm * 4 + t;
            const int arb = wn * 4 + t;
            ph[t] = *(const bf16x8*)(lds + cur + prb * 512 + lof);
            ah[t] = *(const bf16x8*)(lds + cur + 4096 + arb * 512 + lof);
            al[t] = *(const bf16x8*)(lds + cur + 8192 + arb * 512 + lof);
        }
#pragma unroll
        for (int mt = 0; mt < 4; ++mt)
#pragma unroll
            for (int nt = 0; nt < 4; ++nt)
                acc[mt][nt] = __builtin_amdgcn_mfma_f32_32x32x16_bf16(ph[mt], ah[nt], acc[mt][nt], 0, 0, 0);
#pragma unroll
        for (int mt = 0; mt < 4; ++mt)
#pragma unroll
            for (int nt = 0; nt < 4; ++nt)
                acc[mt][nt] = __builtin_amdgcn_mfma_f32_32x32x16_bf16(ph[mt], al[nt], acc[mt][nt], 0, 0, 0);
    }

    // ---- epilogue ----
    // 32x32 C/D layout (m74/m101): col = lane&31, row = (reg&3)+8*(reg>>2)+4*(lane>>5)
#pragma unroll
    for (int mt = 0; mt < 4; ++mt)
#pragma unroll
        for (int reg = 0; reg < 16; ++reg) {
            const int row = r0 + wm * 128 + mt * 32 + (reg & 3) + 8 * (reg >> 2) + 4 * lh;
            u64 best = 0ULL;
#pragma unroll
            for (int nt = 0; nt < 4; ++nt) {
                const int col = c0 + wn * 128 + nt * 32 + l31;
                const float v = acc[mt][nt][reg] * ian[nt];
                const u64 p = ((u64)fkey(v) << 32) | (unsigned int)(~col);
                best = best > p ? best : p;
            }
#pragma unroll
            for (int m = 1; m <= 16; m <<= 1) {
                const u64 o = shfl_xor_u64(best, m);
                best = best > o ? best : o;
            }
            if (l31 == 0) atomicMax(&packed[row], best);
        }
}

// ---------------- fallback fp32 path (proven R1) ----------------
__global__ __launch_bounds__(256) void norms_kernel(const float* __restrict__ x,
                                                    float* __restrict__ inv_an,
                                                    u64* __restrict__ packed) {
    int gid  = blockIdx.x * 256 + threadIdx.x;
    int j    = gid >> 6;
    int lane = threadIdx.x & 63;
    if (gid < NROWS) packed[gid] = 0ULL;
    const float4* a = (const float4*)(x + (size_t)j * XSTR + DDIM);
    float s = 0.0f;
#pragma unroll
    for (int i = 0; i < 4; ++i) {
        float4 v = a[lane + i * 64];
        s += v.x * v.x + v.y * v.y + v.z * v.z + v.w * v.w;
    }
#pragma unroll
    for (int off = 32; off > 0; off >>= 1) s += __shfl_down(s, off, 64);
    if (lane == 0) inv_an[j] = 1.0f / sqrtf(s);
}

__global__ __launch_bounds__(256) void gemm_argmax_kernel(const float* __restrict__ x,
                                                          const float* __restrict__ inv_an,
                                                          u64* __restrict__ packed) {
    __shared__ __align__(16) float Pt[16][128];
    __shared__ __align__(16) float At[16][128];
    const int r0 = blockIdx.x * 128;
    const int c0 = blockIdx.y * 128;
    const int t = threadIdx.x;
    const int tx = t & 15;
    const int ty = t >> 4;
    const int srow = t >> 1;
    const int skq = (t & 1) * 8;
    float acc[8][8];
#pragma unroll
    for (int r = 0; r < 8; ++r)
#pragma unroll
        for (int c = 0; c < 8; ++c) acc[r][c] = 0.0f;
    const float* gp = x + (size_t)(r0 + srow) * XSTR + skq;
    const float* ga = x + (size_t)(c0 + srow) * XSTR + DDIM + skq;
    for (int k0 = 0; k0 < DDIM; k0 += 16) {
        __syncthreads();
        float4 p0 = *(const float4*)(gp + k0);
        float4 p1 = *(const float4*)(gp + k0 + 4);
        float4 a0 = *(const float4*)(ga + k0);
        float4 a1 = *(const float4*)(ga + k0 + 4);
        Pt[skq + 0][srow] = p0.x; Pt[skq + 1][srow] = p0.y;
        Pt[skq + 2][srow] = p0.z; Pt[skq + 3][srow] = p0.w;
        Pt[skq + 4][srow] = p1.x; Pt[skq + 5][srow] = p1.y;
        Pt[skq + 6][srow] = p1.z; Pt[skq + 7][srow] = p1.w;
        At[skq + 0][srow] = a0.x; At[skq + 1][srow] = a0.y;
        At[skq + 2][srow] = a0.z; At[skq + 3][srow] = a0.w;
        At[skq + 4][srow] = a1.x; At[skq + 5][srow] = a1.y;
        At[skq + 6][srow] = a1.z; At[skq + 7][srow] = a1.w;
        __syncthreads();
#pragma unroll
        for (int kk = 0; kk < 16; ++kk) {
            float pr[8], ar[8];
            *(float4*)&pr[0] = *(const float4*)&Pt[kk][ty * 8];
            *(float4*)&pr[4] = *(const float4*)&Pt[kk][ty * 8 + 4];
            *(float4*)&ar[0] = *(const float4*)&At[kk][tx * 8];
            *(float4*)&ar[4] = *(const float4*)&At[kk][tx * 8 + 4];
#pragma unroll
            for (int r = 0; r < 8; ++r)
#pragma unroll
                for (int c = 0; c < 8; ++c) acc[r][c] += pr[r] * ar[c];
        }
    }
    float ian[8];
#pragma unroll
    for (int c = 0; c < 8; ++c) ian[c] = inv_an[c0 + tx * 8 + c];
#pragma unroll
    for (int r = 0; r < 8; ++r) {
        int row = r0 + ty * 8 + r;
        u64 best = 0ULL;
#pragma unroll
        for (int c = 0; c < 8; ++c) {
            int col = c0 + tx * 8 + c;
            float v = acc[r][c] * ian[c];
            u64 p = ((u64)fkey(v) << 32) | (unsigned int)(~col);
            best = best > p ? best : p;
        }
#pragma unroll
        for (int m = 1; m <= 8; m <<= 1) {
            u64 o = shfl_xor_u64(best, m);
            best = best > o ? best : o;
        }
        if (tx == 0) atomicMax(&packed[row], best);
    }
}

// ---------------- finalize ----------------
__global__ __launch_bounds__(256) void finalize_kernel(const u64* __restrict__ packed,
                                                       float* __restrict__ out) {
    __shared__ int cnt_s;
    int t = threadIdx.x;
    if (t == 0) cnt_s = 0;
    __syncthreads();
    int c = 0;
    for (int r = t; r < NROWS; r += 256) {
        unsigned int col = ~(unsigned int)(packed[r] & 0xFFFFFFFFULL);
        c += (col == (unsigned int)r) ? 1 : 0;
    }
#pragma unroll
    for (int off = 32; off > 0; off >>= 1) c += __shfl_down(c, off, 64);
    if ((t & 63) == 0) atomicAdd(&cnt_s, c);
    __syncthreads();
    if (t == 0) {
        out[0] = 1.0f;
        out[1] = 100.0f * (float)cnt_s / (float)NROWS;
    }
}

extern "C" void kernel_launch(void* const* d_in, const int* in_sizes, int n_in,
                              void* d_out, int out_size, void* d_ws, size_t ws_size,
                              hipStream_t stream) {
    (void)in_sizes; (void)n_in; (void)out_size;
    const float* x = (const float*)d_in[0];
    float* out = (float*)d_out;

    if (ws_size >= (size_t)WS_NEED) {
        char* ws = (char*)d_ws;
        unsigned short* Phi = (unsigned short*)(ws + PHI_OFF);
        unsigned short* Ahi = (unsigned short*)(ws + AHI_OFF);
        unsigned short* Alo = (unsigned short*)(ws + ALO_OFF);
        float* inv_an = (float*)(ws + INV_OFF);
        u64* packed = (u64*)(ws + PCK_OFF);

        prep_kernel<<<NROWS, 256, 0, stream>>>(x, Phi, Ahi, Alo, inv_an, packed);
        dim3 grid(NROWS / 256, NROWS / 256);
        mfma_gemm_argmax<<<grid, 256, 0, stream>>>(Phi, Ahi, Alo, inv_an, packed);
        finalize_kernel<<<1, 256, 0, stream>>>(packed, out);
    } else {
        float* inv_an = (float*)d_ws;
        u64* packed = (u64*)((char*)d_ws + NROWS * sizeof(float));
        norms_kernel<<<NROWS / 4, 256, 0, stream>>>(x, inv_an, packed);
        dim3 grid(NROWS / 128, NROWS / 128);
        gemm_argmax_kernel<<<grid, 256, 0, stream>>>(x, inv_an, packed);
        finalize_kernel<<<1, 256, 0, stream>>>(packed, out);
    }
}

// Round 7
// 161.487 us; speedup vs baseline: 1.2685x; 1.0063x over previous
//
#include <hip/hip_runtime.h>

// x (4096, 2, 1024) fp32.  P_i = x[i,0,:], A_j = x[i,1,:]
// out[0] = 1.0 exactly; out[1] = prec1 = 100*mean(argmax_j sim[i,j] == i)
// argmax_j sim[i,j] == argmax_j dot(P_i,A_j)*inv_norm(A_j).
// R7: 2-pass bf16-split MFMA (Phi*Ahi + Phi*Alo). 256x256 block tile,
// 4 waves of 128x128, 32x32x16 MFMA. BK=32 (2x staged bytes in flight per
// barrier, 32 barriers not 64), double-buffered 2x48KB LDS, XCD-swizzled
// 1-D grid (4x8 tile region per XCD -> staging hits XCD L2).

#define NROWS 4096
#define DDIM  1024
#define XSTR  2048

typedef unsigned int u32;
typedef unsigned long long u64;
typedef __attribute__((ext_vector_type(8))) short bf16x8;
typedef __attribute__((ext_vector_type(16))) float f32x16;

#define GLOBAL_AS __attribute__((address_space(1)))
#define LDS_AS    __attribute__((address_space(3)))

__device__ __forceinline__ void async_load16(const void* g, void* l) {
    __builtin_amdgcn_global_load_lds((GLOBAL_AS const u32*)g, (LDS_AS u32*)l, 16, 0, 0);
}

__device__ __forceinline__ unsigned int fkey(float f) {
    unsigned int u = __float_as_uint(f);
    return (u & 0x80000000u) ? ~u : (u | 0x80000000u);
}

__device__ __forceinline__ u64 shfl_xor_u64(u64 v, int m) {
    unsigned int lo = (unsigned int)v;
    unsigned int hi = (unsigned int)(v >> 32);
    lo = __shfl_xor(lo, m, 64);
    hi = __shfl_xor(hi, m, 64);
    return ((u64)hi << 32) | lo;
}

__device__ __forceinline__ unsigned short f2bf(float f) {
    unsigned u = __float_as_uint(f);
    return (unsigned short)((u + 0x7FFFu + ((u >> 16) & 1u)) >> 16);
}

__device__ __forceinline__ void split4(float4 v, ushort4* h, ushort4* l) {
    float f[4] = {v.x, v.y, v.z, v.w};
    unsigned short hh[4], ll[4];
#pragma unroll
    for (int q = 0; q < 4; ++q) {
        hh[q] = f2bf(f[q]);
        float hf = __uint_as_float(((unsigned)hh[q]) << 16);
        ll[q] = f2bf(f[q] - hf);
    }
    *h = make_ushort4(hh[0], hh[1], hh[2], hh[3]);
    *l = make_ushort4(ll[0], ll[1], ll[2], ll[3]);
}

// Workspace layout (bytes):
#define PHI_OFF 0u
#define AHI_OFF 8388608u
#define ALO_OFF 16777216u
#define INV_OFF 25165824u
#define PCK_OFF 25182208u
#define WS_NEED 25214976u

// Prep: one block per row. Phi = bf16(P); A split into (Ahi, Alo);
// block-reduce anchor norm (from fp32); zero packed[row].
__global__ __launch_bounds__(256) void prep_kernel(const float* __restrict__ x,
                                                   unsigned short* __restrict__ Phi,
                                                   unsigned short* __restrict__ Ahi,
                                                   unsigned short* __restrict__ Alo,
                                                   float* __restrict__ inv_an,
                                                   u64* __restrict__ packed) {
    __shared__ float red[4];
    const int b = blockIdx.x;
    const int t = threadIdx.x;

    float4 pv = *(const float4*)(x + (size_t)b * XSTR + t * 4);
    float4 av = *(const float4*)(x + (size_t)b * XSTR + DDIM + t * 4);

    ushort4 ph = make_ushort4(f2bf(pv.x), f2bf(pv.y), f2bf(pv.z), f2bf(pv.w));
    ((ushort4*)Phi)[(size_t)b * 256 + t] = ph;

    ushort4 h, l;
    split4(av, &h, &l);
    ((ushort4*)Ahi)[(size_t)b * 256 + t] = h;
    ((ushort4*)Alo)[(size_t)b * 256 + t] = l;

    float s = av.x * av.x + av.y * av.y + av.z * av.z + av.w * av.w;
#pragma unroll
    for (int off = 32; off > 0; off >>= 1) s += __shfl_down(s, off, 64);
    if ((t & 63) == 0) red[t >> 6] = s;
    __syncthreads();
    if (t == 0) {
        inv_an[b] = 1.0f / sqrtf(red[0] + red[1] + red[2] + red[3]);
        packed[b] = 0ULL;
    }
}

// MFMA GEMM + argmax. 256x256 block tile, 4 waves (2x2) of 128x128.
// BK=32: per buffer 48 segs x 1KB, seg = 32 rows x 16 k at byte q*512+r*16
// (the order global_load_lds produces: lane i = q*32+r writes base+i*16).
// Buffer layout (ushort units): arr(0=Phi,1=Ahi,2=Alo)*8192 + (rb*2+kh)*512.
// All 4 waves stage 12 segs each. XCD swizzle: bid&7 = XCD, each XCD owns a
// 4(r) x 8(c) region of the 16x16 tile grid.
__global__ __launch_bounds__(256, 1) void mfma_gemm_argmax(const unsigned short* __restrict__ Phi,
                                                           const unsigned short* __restrict__ Ahi,
                                                           const unsigned short* __restrict__ Alo,
                                                           const float* __restrict__ inv_an,
                                                           u64* __restrict__ packed) {
    __shared__ __align__(16) unsigned short lds[49152];  // 2 bufs x 24576 ushort (48KB each)

    const int bid = blockIdx.x;
    const int xcd = bid & 7;
    const int slt = bid >> 3;                       // 0..31
    const int rblk = (xcd >> 1) * 4 + (slt >> 3);   // 0..15
    const int cblk = (xcd & 1) * 8 + (slt & 7);     // 0..15
    const int r0 = rblk * 256;
    const int c0 = cblk * 256;

    const int wave = threadIdx.x >> 6;
    const int lane = threadIdx.x & 63;
    const int l31 = lane & 31;
    const int lh = lane >> 5;
    const int wm = wave & 1;   // m-half: rows wm*128..+127
    const int wn = wave >> 1;  // n-half: cols wn*128..+127

    // ---- staging: 48 segs (arr*16 + rb*2 + kh), wave w stages [w*12, w*12+12) ----
    const unsigned short* srcs[3] = {Phi, Ahi, Alo};
    const char* gp[12];
    int ldst[12];  // LDS ushort offset within buffer
#pragma unroll
    for (int j = 0; j < 12; ++j) {
        const int g = wave * 12 + j;
        const int arr = g >> 4;
        const int rb = (g & 15) >> 1;
        const int kh = g & 1;
        const int baserow = (arr == 0) ? r0 : c0;
        gp[j] = (const char*)(srcs[arr] + (size_t)(baserow + rb * 32 + l31) * DDIM + kh * 16) + lh * 16;
        ldst[j] = g * 512;
    }

    // frag read offset within a 1KB seg (ushort units): byte lh*512+l31*16
    const int lof = lh * 256 + l31 * 8;

    f32x16 zero16 = {0.f,0.f,0.f,0.f,0.f,0.f,0.f,0.f,0.f,0.f,0.f,0.f,0.f,0.f,0.f,0.f};
    f32x16 acc[4][4];
#pragma unroll
    for (int i = 0; i < 4; ++i)
#pragma unroll
        for (int j = 0; j < 4; ++j) acc[i][j] = zero16;

    float ian[4];
#pragma unroll
    for (int nt = 0; nt < 4; ++nt) ian[nt] = inv_an[c0 + wn * 128 + nt * 32 + l31];

    // prologue: stage chunk 0 -> buf 0
#pragma unroll
    for (int j = 0; j < 12; ++j) async_load16(gp[j], lds + ldst[j]);

    for (int kc = 0; kc < 32; ++kc) {
        __syncthreads();  // vmcnt drained: chunk kc visible in buf kc&1
        const int cur = (kc & 1) * 24576;
        if (kc < 31) {
            const int nxt = ((kc + 1) & 1) * 24576;
            const int gofs = (kc + 1) * 64;  // bytes: 32 k * 2B
#pragma unroll
            for (int j = 0; j < 12; ++j)
                async_load16(gp[j] + gofs, lds + nxt + ldst[j]);
        }

#pragma unroll
        for (int kh = 0; kh < 2; ++kh) {
            bf16x8 ph[4], ah[4], al[4];
#pragma unroll
            for (int t = 0; t < 4; ++t) {
                const int prb = wm * 4 + t;
                const int arb = wn * 4 + t;
                ph[t] = *(const bf16x8*)(lds + cur + (prb * 2 + kh) * 512 + lof);
                ah[t] = *(const bf16x8*)(lds + cur + 8192 + (arb * 2 + kh) * 512 + lof);
                al[t] = *(const bf16x8*)(lds + cur + 16384 + (arb * 2 + kh) * 512 + lof);
            }
#pragma unroll
            for (int mt = 0; mt < 4; ++mt)
#pragma unroll
                for (int nt = 0; nt < 4; ++nt)
                    acc[mt][nt] = __builtin_amdgcn_mfma_f32_32x32x16_bf16(ph[mt], ah[nt], acc[mt][nt], 0, 0, 0);
#pragma unroll
            for (int mt = 0; mt < 4; ++mt)
#pragma unroll
                for (int nt = 0; nt < 4; ++nt)
                    acc[mt][nt] = __builtin_amdgcn_mfma_f32_32x32x16_bf16(ph[mt], al[nt], acc[mt][nt], 0, 0, 0);
        }
    }

    // ---- epilogue ----
    // 32x32 C/D layout (m74/m101): col = lane&31, row = (reg&3)+8*(reg>>2)+4*(lane>>5)
#pragma unroll
    for (int mt = 0; mt < 4; ++mt)
#pragma unroll
        for (int reg = 0; reg < 16; ++reg) {
            const int row = r0 + wm * 128 + mt * 32 + (reg & 3) + 8 * (reg >> 2) + 4 * lh;
            u64 best = 0ULL;
#pragma unroll
            for (int nt = 0; nt < 4; ++nt) {
                const int col = c0 + wn * 128 + nt * 32 + l31;
                const float v = acc[mt][nt][reg] * ian[nt];
                const u64 p = ((u64)fkey(v) << 32) | (unsigned int)(~col);
                best = best > p ? best : p;
            }
#pragma unroll
            for (int m = 1; m <= 16; m <<= 1) {
                const u64 o = shfl_xor_u64(best, m);
                best = best > o ? best : o;
            }
            if (l31 == 0) atomicMax(&packed[row], best);
        }
}

// ---------------- fallback fp32 path (proven R1) ----------------
__global__ __launch_bounds__(256) void norms_kernel(const float* __restrict__ x,
                                                    float* __restrict__ inv_an,
                                                    u64* __restrict__ packed) {
    int gid  = blockIdx.x * 256 + threadIdx.x;
    int j    = gid >> 6;
    int lane = threadIdx.x & 63;
    if (gid < NROWS) packed[gid] = 0ULL;
    const float4* a = (const float4*)(x + (size_t)j * XSTR + DDIM);
    float s = 0.0f;
#pragma unroll
    for (int i = 0; i < 4; ++i) {
        float4 v = a[lane + i * 64];
        s += v.x * v.x + v.y * v.y + v.z * v.z + v.w * v.w;
    }
#pragma unroll
    for (int off = 32; off > 0; off >>= 1) s += __shfl_down(s, off, 64);
    if (lane == 0) inv_an[j] = 1.0f / sqrtf(s);
}

__global__ __launch_bounds__(256) void gemm_argmax_kernel(const float* __restrict__ x,
                                                          const float* __restrict__ inv_an,
                                                          u64* __restrict__ packed) {
    __shared__ __align__(16) float Pt[16][128];
    __shared__ __align__(16) float At[16][128];
    const int r0 = blockIdx.x * 128;
    const int c0 = blockIdx.y * 128;
    const int t = threadIdx.x;
    const int tx = t & 15;
    const int ty = t >> 4;
    const int srow = t >> 1;
    const int skq = (t & 1) * 8;
    float acc[8][8];
#pragma unroll
    for (int r = 0; r < 8; ++r)
#pragma unroll
        for (int c = 0; c < 8; ++c) acc[r][c] = 0.0f;
    const float* gp = x + (size_t)(r0 + srow) * XSTR + skq;
    const float* ga = x + (size_t)(c0 + srow) * XSTR + DDIM + skq;
    for (int k0 = 0; k0 < DDIM; k0 += 16) {
        __syncthreads();
        float4 p0 = *(const float4*)(gp + k0);
        float4 p1 = *(const float4*)(gp + k0 + 4);
        float4 a0 = *(const float4*)(ga + k0);
        float4 a1 = *(const float4*)(ga + k0 + 4);
        Pt[skq + 0][srow] = p0.x; Pt[skq + 1][srow] = p0.y;
        Pt[skq + 2][srow] = p0.z; Pt[skq + 3][srow] = p0.w;
        Pt[skq + 4][srow] = p1.x; Pt[skq + 5][srow] = p1.y;
        Pt[skq + 6][srow] = p1.z; Pt[skq + 7][srow] = p1.w;
        At[skq + 0][srow] = a0.x; At[skq + 1][srow] = a0.y;
        At[skq + 2][srow] = a0.z; At[skq + 3][srow] = a0.w;
        At[skq + 4][srow] = a1.x; At[skq + 5][srow] = a1.y;
        At[skq + 6][srow] = a1.z; At[skq + 7][srow] = a1.w;
        __syncthreads();
#pragma unroll
        for (int kk = 0; kk < 16; ++kk) {
            float pr[8], ar[8];
            *(float4*)&pr[0] = *(const float4*)&Pt[kk][ty * 8];
            *(float4*)&pr[4] = *(const float4*)&Pt[kk][ty * 8 + 4];
            *(float4*)&ar[0] = *(const float4*)&At[kk][tx * 8];
            *(float4*)&ar[4] = *(const float4*)&At[kk][tx * 8 + 4];
#pragma unroll
            for (int r = 0; r < 8; ++r)
#pragma unroll
                for (int c = 0; c < 8; ++c) acc[r][c] += pr[r] * ar[c];
        }
    }
    float ian[8];
#pragma unroll
    for (int c = 0; c < 8; ++c) ian[c] = inv_an[c0 + tx * 8 + c];
#pragma unroll
    for (int r = 0; r < 8; ++r) {
        int row = r0 + ty * 8 + r;
        u64 best = 0ULL;
#pragma unroll
        for (int c = 0; c < 8; ++c) {
            int col = c0 + tx * 8 + c;
            float v = acc[r][c] * ian[c];
            u64 p = ((u64)fkey(v) << 32) | (unsigned int)(~col);
            best = best > p ? best : p;
        }
#pragma unroll
        for (int m = 1; m <= 8; m <<= 1) {
            u64 o = shfl_xor_u64(best, m);
            best = best > o ? best : o;
        }
        if (tx == 0) atomicMax(&packed[row], best);
    }
}

// ---------------- finalize ----------------
__global__ __launch_bounds__(256) void finalize_kernel(const u64* __restrict__ packed,
                                                       float* __restrict__ out) {
    __shared__ int cnt_s;
    int t = threadIdx.x;
    if (t == 0) cnt_s = 0;
    __syncthreads();
    int c = 0;
    for (int r = t; r < NROWS; r += 256) {
        unsigned int col = ~(unsigned int)(packed[r] & 0xFFFFFFFFULL);
        c += (col == (unsigned int)r) ? 1 : 0;
    }
#pragma unroll
    for (int off = 32; off > 0; off >>= 1) c += __shfl_down(c, off, 64);
    if ((t & 63) == 0) atomicAdd(&cnt_s, c);
    __syncthreads();
    if (t == 0) {
        out[0] = 1.0f;
        out[1] = 100.0f * (float)cnt_s / (float)NROWS;
    }
}

extern "C" void kernel_launch(void* const* d_in, const int* in_sizes, int n_in,
                              void* d_out, int out_size, void* d_ws, size_t ws_size,
                              hipStream_t stream) {
    (void)in_sizes; (void)n_in; (void)out_size;
    const float* x = (const float*)d_in[0];
    float* out = (float*)d_out;

    if (ws_size >= (size_t)WS_NEED) {
        char* ws = (char*)d_ws;
        unsigned short* Phi = (unsigned short*)(ws + PHI_OFF);
        unsigned short* Ahi = (unsigned short*)(ws + AHI_OFF);
        unsigned short* Alo = (unsigned short*)(ws + ALO_OFF);
        float* inv_an = (float*)(ws + INV_OFF);
        u64* packed = (u64*)(ws + PCK_OFF);

        prep_kernel<<<NROWS, 256, 0, stream>>>(x, Phi, Ahi, Alo, inv_an, packed);
        mfma_gemm_argmax<<<256, 256, 0, stream>>>(Phi, Ahi, Alo, inv_an, packed);
        finalize_kernel<<<1, 256, 0, stream>>>(packed, out);
    } else {
        float* inv_an = (float*)d_ws;
        u64* packed = (u64*)((char*)d_ws + NROWS * sizeof(float));
        norms_kernel<<<NROWS / 4, 256, 0, stream>>>(x, inv_an, packed);
        dim3 grid(NROWS / 128, NROWS / 128);
        gemm_argmax_kernel<<<grid, 256, 0, stream>>>(x, inv_an, packed);
        finalize_kernel<<<1, 256, 0, stream>>>(packed, out);
    }
}